// Round 16
// baseline (384.497 us; speedup 1.0000x reference)
//
#include <hip/hip_runtime.h>

// ComplexMultiheadAttention: B=8,S=1024,F=512,E=512,H=8,C=64
// Round 16: SINGLE-PASS fused attention. r15 (Q-regs, 3-sync) regressed
// (290us, VGPR 144, occ 11.8%) -> reverted to r12's verified structure
// (128-row, Q in LDS, K/P overlay, 4 syncs/tile, VGPR 120, 69.6KB LDS).
// Structural change instead: softmax needs NO max pass (scores >= 0,
// bounded ~11) -> ONE pass writes UNNORMALIZED p=exp(mag) to attn,
// accumulates row sums + PV together; av scaled by 1/sum in epilogue
// (sums in regs; sinv[128] LDS bridges score-rows -> PV-rows). New
// normalize_k does the row-scale RMW on attn, re-deriving sums from the
// data it reads anyway (no cross-kernel state, ws guard unchanged 64MiB).
// Removes: 16 tiles of score MFMA (43 GF), 67M exp/sqrt, 32 barriers.

namespace {
constexpr int Bn = 8, Sn = 1024, Fn = 512, En = 512, Hn = 8, Cn = 64;
constexpr int Mn = Bn * Sn;                       // 8192
constexpr int Qszi = Bn * Hn * Sn * Cn;           // 4,194,304 per plane
constexpr size_t Qsz = (size_t)Qszi;
constexpr int XLIM = Bn * Sn * Fn;                // floats per x plane
constexpr int WLIM = En * Fn;                     // floats per weight plane
constexpr size_t OUT1 = (size_t)Bn * Sn * Fn;     // complex elems in out   (4,194,304)
constexpr size_t ATT1 = (size_t)Bn * Hn * Sn * Sn;// complex elems in attn (67,108,864)
constexpr float RDIV = 0.08838834764831845f;      // 1/sqrt(2*C) = 1/sqrt(128)
}

typedef __attribute__((ext_vector_type(8))) short short8v;  // 8 bf16 (4 VGPRs)
typedef __attribute__((ext_vector_type(4))) float f32x4;

__device__ __forceinline__ float bf2f(unsigned short u) {
    union { unsigned int u32; float f; } c; c.u32 = (unsigned int)u << 16; return c.f;
}
__device__ __forceinline__ unsigned short f2bf(float f) {
    union { float f; unsigned int u; } c; c.f = f;
    unsigned int r = (c.u + 0x7FFFu + ((c.u >> 16) & 1u)) >> 16;  // RNE
    return (unsigned short)r;
}
__device__ __forceinline__ unsigned int packbf(float lo, float hi) {
    return (unsigned int)f2bf(lo) | ((unsigned int)f2bf(hi) << 16);
}
__device__ __forceinline__ short8v neg8(short8v v) {
    union { short8v s; unsigned int u[4]; } c; c.s = v;
    #pragma unroll
    for (int j = 0; j < 4; ++j) c.u[j] ^= 0x80008000u;
    return c.s;
}
__device__ __forceinline__ float4 ld4(const float* p) { return *(const float4*)p; }

// ================= shared MFMA inner body (complex x complex, pad-40 tiles) ====
template<bool CONJB>
__device__ __forceinline__ void mfma_body(
    const short (*As_r)[40], const short (*As_i)[40],
    const short (*Bs_r)[40], const short (*Bs_i)[40],
    int wr, int wn, int lrow, int lk,
    f32x4 accr[4][2], f32x4 acci[4][2])
{
    short8v a_r[4], a_i[4], a_x[4];
    #pragma unroll
    for (int fm = 0; fm < 4; ++fm) {
        a_r[fm] = *(const short8v*)&As_r[wr*64 + fm*16 + lrow][lk];
        a_i[fm] = *(const short8v*)&As_i[wr*64 + fm*16 + lrow][lk];
        a_x[fm] = neg8(CONJB ? a_r[fm] : a_i[fm]);
    }
    short8v b_r[2], b_i[2];
    #pragma unroll
    for (int fn = 0; fn < 2; ++fn) {
        b_r[fn] = *(const short8v*)&Bs_r[wn*32 + fn*16 + lrow][lk];
        b_i[fn] = *(const short8v*)&Bs_i[wn*32 + fn*16 + lrow][lk];
    }
    __builtin_amdgcn_s_setprio(1);
    #pragma unroll
    for (int fm = 0; fm < 4; ++fm)
        #pragma unroll
        for (int fn = 0; fn < 2; ++fn) {
            accr[fm][fn] = __builtin_amdgcn_mfma_f32_16x16x32_bf16(
                a_r[fm], b_r[fn], accr[fm][fn], 0, 0, 0);
            accr[fm][fn] = __builtin_amdgcn_mfma_f32_16x16x32_bf16(
                CONJB ? a_i[fm] : a_x[fm], b_i[fn], accr[fm][fn], 0, 0, 0);
            acci[fm][fn] = __builtin_amdgcn_mfma_f32_16x16x32_bf16(
                CONJB ? a_x[fm] : a_r[fm], b_i[fn], acci[fm][fn], 0, 0, 0);
            acci[fm][fn] = __builtin_amdgcn_mfma_f32_16x16x32_bf16(
                a_i[fm], b_r[fn], acci[fm][fn], 0, 0, 0);
        }
    __builtin_amdgcn_s_setprio(0);
}

// ===== MFMA complex NT GEMM, fp32 x fp32 (convert at staging) — qkv_proj =====
template<bool CONJB>
__device__ __forceinline__ void cgemm_mfma(
    const float* __restrict__ Ar, const float* __restrict__ Ai, int arow0, int lda,
    const float* __restrict__ Br, const float* __restrict__ Bi, int brow0, int ldb,
    int K, f32x4 accr[4][2], f32x4 acci[4][2])
{
    __shared__ short As_r[128][40], As_i[128][40];
    __shared__ short Bs_r[64][40],  Bs_i[64][40];
    const int tid = threadIdx.x;
    const int sar = tid >> 1, sac = (tid & 1) * 16;
    const int sbr = tid >> 2, sbc = (tid & 3) * 8;
    const int wid = tid >> 6, lane = tid & 63;
    const int wr = wid >> 1, wn = wid & 1;
    const int lrow = lane & 15, lk = (lane >> 4) * 8;

    for (int k0 = 0; k0 < K; k0 += 32) {
        const float* pAr = Ar + (size_t)(arow0 + sar) * lda + k0 + sac;
        const float* pAi = Ai + (size_t)(arow0 + sar) * lda + k0 + sac;
        float4 va_r[4], va_i[4];
        #pragma unroll
        for (int q = 0; q < 4; ++q) { va_r[q] = ld4(pAr + 4*q); va_i[q] = ld4(pAi + 4*q); }
        const float* pBr = Br + (size_t)(brow0 + sbr) * ldb + k0 + sbc;
        const float* pBi = Bi + (size_t)(brow0 + sbr) * ldb + k0 + sbc;
        float4 vb_r[2], vb_i[2];
        #pragma unroll
        for (int q = 0; q < 2; ++q) { vb_r[q] = ld4(pBr + 4*q); vb_i[q] = ld4(pBi + 4*q); }

        __syncthreads();
        #pragma unroll
        for (int q = 0; q < 4; ++q) {
            *(uint2*)&As_r[sar][sac + 4*q] =
                make_uint2(packbf(va_r[q].x, va_r[q].y), packbf(va_r[q].z, va_r[q].w));
            *(uint2*)&As_i[sar][sac + 4*q] =
                make_uint2(packbf(va_i[q].x, va_i[q].y), packbf(va_i[q].z, va_i[q].w));
        }
        #pragma unroll
        for (int q = 0; q < 2; ++q) {
            *(uint2*)&Bs_r[sbr][sbc + 4*q] =
                make_uint2(packbf(vb_r[q].x, vb_r[q].y), packbf(vb_r[q].z, vb_r[q].w));
            *(uint2*)&Bs_i[sbr][sbc + 4*q] =
                make_uint2(packbf(vb_i[q].x, vb_i[q].y), packbf(vb_i[q].z, vb_i[q].w));
        }
        __syncthreads();
        mfma_body<CONJB>(As_r, As_i, Bs_r, Bs_i, wr, wn, lrow, lk, accr, acci);
    }
}

// ===== MFMA complex NT GEMM, A bf16 (direct) x B fp32 (convert) — out_proj =====
template<bool CONJB>
__device__ __forceinline__ void cgemm_mfma_abf16(
    const unsigned short* __restrict__ Ar, const unsigned short* __restrict__ Ai,
    int arow0, int lda,
    const float* __restrict__ Br, const float* __restrict__ Bi, int brow0, int ldb,
    int K, f32x4 accr[4][2], f32x4 acci[4][2])
{
    __shared__ short As_r[128][40], As_i[128][40];
    __shared__ short Bs_r[64][40],  Bs_i[64][40];
    const int tid = threadIdx.x;
    const int sar = tid >> 1, sac = (tid & 1) * 16;
    const int sbr = tid >> 2, sbc = (tid & 3) * 8;
    const int wid = tid >> 6, lane = tid & 63;
    const int wr = wid >> 1, wn = wid & 1;
    const int lrow = lane & 15, lk = (lane >> 4) * 8;

    for (int k0 = 0; k0 < K; k0 += 32) {
        const unsigned short* pAr = Ar + (size_t)(arow0 + sar) * lda + k0 + sac;
        const unsigned short* pAi = Ai + (size_t)(arow0 + sar) * lda + k0 + sac;
        short8v va_r0 = *(const short8v*)pAr;
        short8v va_r1 = *(const short8v*)(pAr + 8);
        short8v va_i0 = *(const short8v*)pAi;
        short8v va_i1 = *(const short8v*)(pAi + 8);
        const float* pBr = Br + (size_t)(brow0 + sbr) * ldb + k0 + sbc;
        const float* pBi = Bi + (size_t)(brow0 + sbr) * ldb + k0 + sbc;
        float4 vb_r[2], vb_i[2];
        #pragma unroll
        for (int q = 0; q < 2; ++q) { vb_r[q] = ld4(pBr + 4*q); vb_i[q] = ld4(pBi + 4*q); }

        __syncthreads();
        *(short8v*)&As_r[sar][sac]     = va_r0;
        *(short8v*)&As_r[sar][sac + 8] = va_r1;
        *(short8v*)&As_i[sar][sac]     = va_i0;
        *(short8v*)&As_i[sar][sac + 8] = va_i1;
        #pragma unroll
        for (int q = 0; q < 2; ++q) {
            *(uint2*)&Bs_r[sbr][sbc + 4*q] =
                make_uint2(packbf(vb_r[q].x, vb_r[q].y), packbf(vb_r[q].z, vb_r[q].w));
            *(uint2*)&Bs_i[sbr][sbc + 4*q] =
                make_uint2(packbf(vb_i[q].x, vb_i[q].y), packbf(vb_i[q].z, vb_i[q].w));
        }
        __syncthreads();
        mfma_body<CONJB>(As_r, As_i, Bs_r, Bs_i, wr, wn, lrow, lk, accr, acci);
    }
}

// ---- diagnostic ----
__global__ void diag_k(float* __restrict__ out, float v) { out[0] = v; }

// ---- K1: QKV projection (MFMA) -> bf16 planes. grid (M/128, E/64, 3) ----
__global__ __launch_bounds__(256) void qkv_proj_k(
    const float* __restrict__ xr, const float* __restrict__ xi,
    const float* __restrict__ wqr, const float* __restrict__ wqi,
    const float* __restrict__ bqr, const float* __restrict__ bqi,
    const float* __restrict__ wkr, const float* __restrict__ wki,
    const float* __restrict__ bkr, const float* __restrict__ bki,
    const float* __restrict__ wvr, const float* __restrict__ wvi,
    const float* __restrict__ bvr, const float* __restrict__ bvi,
    unsigned short* __restrict__ ws)
{
    const int which = blockIdx.z;
    const float* wr_ = which == 0 ? wqr : which == 1 ? wkr : wvr;
    const float* wi_ = which == 0 ? wqi : which == 1 ? wki : wvi;
    const float* br_ = which == 0 ? bqr : which == 1 ? bkr : bvr;
    const float* bi_ = which == 0 ? bqi : which == 1 ? bki : bvi;
    unsigned short* outr = ws + (size_t)which * 2 * Qsz;
    unsigned short* outi = outr + Qsz;

    const int m0 = blockIdx.x * 128, n0 = blockIdx.y * 64;
    f32x4 accr[4][2], acci[4][2];
    const f32x4 z4 = {0.f, 0.f, 0.f, 0.f};
    #pragma unroll
    for (int fm = 0; fm < 4; ++fm)
        #pragma unroll
        for (int fn = 0; fn < 2; ++fn) { accr[fm][fn] = z4; acci[fm][fn] = z4; }

    cgemm_mfma<false>(xr, xi, m0, Fn, wr_, wi_, n0, Fn, Fn, accr, acci);

    const int lane = threadIdx.x & 63, wid = threadIdx.x >> 6;
    const int wr2 = wid >> 1, wn2 = wid & 1;
    #pragma unroll
    for (int fm = 0; fm < 4; ++fm)
        #pragma unroll
        for (int fn = 0; fn < 2; ++fn) {
            const int e = n0 + wn2*32 + fn*16 + (lane & 15);
            const int h = e >> 6, c = e & (Cn - 1);
            const float brv = br_[e], biv = bi_[e];
            #pragma unroll
            for (int r = 0; r < 4; ++r) {
                const int m = m0 + wr2*64 + fm*16 + (lane >> 4)*4 + r;
                const int b = m >> 10, s = m & (Sn - 1);
                const size_t idx = (((size_t)(b * Hn + h)) * Sn + s) * Cn + c;
                outr[idx] = f2bf(accr[fm][fn][r] + brv);
                outi[idx] = f2bf(acci[fm][fn][r] + biv);
            }
        }
}

// ---- K2: fused SINGLE-PASS score+PV. grid (S/128, 64), 256 thr (4 waves) ----
// Writes UNNORMALIZED p=exp(mag/sqrt(2C)) to attn; accumulates row sums and
// PV simultaneously; epilogue scales av by 1/sum (sinv LDS bridges
// score-phase rows -> PV-phase rows). normalize_k fixes attn afterwards.
template<int ST>
__global__ __launch_bounds__(256) void attn_fused_k(
    const unsigned short* __restrict__ qkv, float* __restrict__ attn,
    unsigned short* __restrict__ avb)
{
    const int bh = blockIdx.y;
    const int r0 = blockIdx.x * 128;
    const size_t poff = (size_t)bh * Sn * Cn;
    const unsigned short* qr = qkv + poff;
    const unsigned short* qi = qkv + Qsz + poff;
    const unsigned short* kr = qkv + 2 * Qsz + poff;
    const unsigned short* ki = qkv + 3 * Qsz + poff;
    const unsigned short* vr = qkv + 4 * Qsz + poff;
    const unsigned short* vi = qkv + 5 * Qsz + poff;

    __shared__ short Qr[128][68], Qi[128][68];   // 34 KB, resident
    __shared__ short KP[2][64][68];              // 17 KB: K tile, then P overlays
    __shared__ short Vtr[64][68], Vti[64][68];   // 17 KB: V^T [c][t]
    __shared__ float sinv[128];                  // 512 B: row -> 1/sum
    short (*Ps)[68] = (short(*)[68])KP;          // P [128][68] == KP memory

    const int tid = threadIdx.x;
    const int lane = tid & 63, wid = tid >> 6;
    const int lrow = lane & 15, g = lane >> 4, lk = g * 8;
    const int srow0 = 32 * wid;                  // score-phase: wave owns 32 rows
    const int wr = wid >> 1, wn = wid & 1;       // PV-phase 2x2

    // stage Q once: 128 rows x 64, 2 thr/row
    {
        const int row = tid >> 1, seg = (tid & 1) * 32;
        const unsigned short* pr = qr + (size_t)(r0 + row) * Cn + seg;
        const unsigned short* pi = qi + (size_t)(r0 + row) * Cn + seg;
        #pragma unroll
        for (int q = 0; q < 4; ++q) {
            *(short8v*)&Qr[row][seg + 8*q] = *(const short8v*)(pr + 8*q);
            *(short8v*)&Qi[row][seg + 8*q] = *(const short8v*)(pi + 8*q);
        }
    }
    const int kst_row = tid >> 2, kst_seg = (tid & 3) * 16;  // K stage: 4 thr/row
    const int vst_t = tid & 63, vst_c = (tid >> 6) * 16;     // V stage: 1 thr/t-row

    float ssum[2][4] = {};
    f32x4 pvr[4][2], pvi[4][2];
    const f32x4 z4 = {0.f, 0.f, 0.f, 0.f};
    #pragma unroll
    for (int fm = 0; fm < 4; ++fm)
        #pragma unroll
        for (int fn = 0; fn < 2; ++fn) { pvr[fm][fn] = z4; pvi[fm][fn] = z4; }

    __syncthreads();  // Q ready

    // ---------- SINGLE PASS over t-tiles ----------
    for (int t0 = 0; t0 < Sn; t0 += 64) {
        short8v k_r0 = *(const short8v*)(kr + (size_t)(t0 + kst_row) * Cn + kst_seg);
        short8v k_r1 = *(const short8v*)(kr + (size_t)(t0 + kst_row) * Cn + kst_seg + 8);
        short8v k_i0 = *(const short8v*)(ki + (size_t)(t0 + kst_row) * Cn + kst_seg);
        short8v k_i1 = *(const short8v*)(ki + (size_t)(t0 + kst_row) * Cn + kst_seg + 8);
        short8v v_r0 = *(const short8v*)(vr + (size_t)(t0 + vst_t) * Cn + vst_c);
        short8v v_r1 = *(const short8v*)(vr + (size_t)(t0 + vst_t) * Cn + vst_c + 8);
        short8v v_i0 = *(const short8v*)(vi + (size_t)(t0 + vst_t) * Cn + vst_c);
        short8v v_i1 = *(const short8v*)(vi + (size_t)(t0 + vst_t) * Cn + vst_c + 8);
        __syncthreads();  // prev PV reads done
        *(short8v*)&KP[0][kst_row][kst_seg]     = k_r0;
        *(short8v*)&KP[0][kst_row][kst_seg + 8] = k_r1;
        *(short8v*)&KP[1][kst_row][kst_seg]     = k_i0;
        *(short8v*)&KP[1][kst_row][kst_seg + 8] = k_i1;
        #pragma unroll
        for (int j = 0; j < 8; ++j) {
            Vtr[vst_c + j][vst_t] = v_r0[j];
            Vtr[vst_c + 8 + j][vst_t] = v_r1[j];
            Vti[vst_c + j][vst_t] = v_i0[j];
            Vti[vst_c + 8 + j][vst_t] = v_i1[j];
        }
        __syncthreads();

        f32x4 cr[2][4], ci[2][4];
        #pragma unroll
        for (int fm = 0; fm < 2; ++fm)
            #pragma unroll
            for (int fn = 0; fn < 4; ++fn) { cr[fm][fn] = z4; ci[fm][fn] = z4; }
        #pragma unroll
        for (int kh = 0; kh < 2; ++kh) {
            const int kof = kh*32 + lk;
            short8v br_[4], bi_[4];
            #pragma unroll
            for (int fn = 0; fn < 4; ++fn) {
                br_[fn] = *(const short8v*)&KP[0][fn*16 + lrow][kof];
                bi_[fn] = *(const short8v*)&KP[1][fn*16 + lrow][kof];
            }
            __builtin_amdgcn_s_setprio(1);
            #pragma unroll
            for (int fm = 0; fm < 2; ++fm) {
                short8v ar = *(const short8v*)&Qr[srow0 + fm*16 + lrow][kof];
                short8v ai = *(const short8v*)&Qi[srow0 + fm*16 + lrow][kof];
                short8v ax = neg8(ar);
                #pragma unroll
                for (int fn = 0; fn < 4; ++fn) {
                    cr[fm][fn] = __builtin_amdgcn_mfma_f32_16x16x32_bf16(ar, br_[fn], cr[fm][fn], 0,0,0);
                    cr[fm][fn] = __builtin_amdgcn_mfma_f32_16x16x32_bf16(ai, bi_[fn], cr[fm][fn], 0,0,0);
                    ci[fm][fn] = __builtin_amdgcn_mfma_f32_16x16x32_bf16(ai, br_[fn], ci[fm][fn], 0,0,0);
                    ci[fm][fn] = __builtin_amdgcn_mfma_f32_16x16x32_bf16(ax, bi_[fn], ci[fm][fn], 0,0,0);
                }
            }
            __builtin_amdgcn_s_setprio(0);
        }
        // unnormalized p: write attn + accumulate row sums + stash for staging
        float pval[2][4][4];
        #pragma unroll
        for (int fm = 0; fm < 2; ++fm)
            #pragma unroll
            for (int fn = 0; fn < 4; ++fn) {
                const int t = t0 + fn*16 + lrow;
                #pragma unroll
                for (int rr = 0; rr < 4; ++rr) {
                    const float re = cr[fm][fn][rr], im = ci[fm][fn][rr];
                    const float p = __expf(sqrtf(fmaf(re, re, im*im)) * RDIV);
                    pval[fm][fn][rr] = p;
                    ssum[fm][rr] += p;
                    const size_t row = (size_t)bh * Sn + r0 + srow0 + fm*16 + g*4 + rr;
                    const size_t idx = (row * Sn + t) * (size_t)ST;
                    if (ST == 2) *(float2*)&attn[idx] = make_float2(p, 0.f);
                    else         attn[idx] = p;
                }
            }
        __syncthreads();  // all waves done reading K -> safe to overlay with P
        #pragma unroll
        for (int fm = 0; fm < 2; ++fm)
            #pragma unroll
            for (int fn = 0; fn < 4; ++fn)
                #pragma unroll
                for (int rr = 0; rr < 4; ++rr)
                    Ps[srow0 + fm*16 + g*4 + rr][fn*16 + lrow] = f2bf(pval[fm][fn][rr]);
        __syncthreads();  // P + V ready

        #pragma unroll
        for (int kh = 0; kh < 2; ++kh) {
            const int kof = kh*32 + lk;
            short8v bR[2], bI[2];
            #pragma unroll
            for (int fn = 0; fn < 2; ++fn) {
                bR[fn] = *(const short8v*)&Vtr[wn*32 + fn*16 + lrow][kof];
                bI[fn] = *(const short8v*)&Vti[wn*32 + fn*16 + lrow][kof];
            }
            __builtin_amdgcn_s_setprio(1);
            #pragma unroll
            for (int fm = 0; fm < 4; ++fm) {
                short8v pA = *(const short8v*)&Ps[wr*64 + fm*16 + lrow][kof];
                #pragma unroll
                for (int fn = 0; fn < 2; ++fn) {
                    pvr[fm][fn] = __builtin_amdgcn_mfma_f32_16x16x32_bf16(pA, bR[fn], pvr[fm][fn], 0,0,0);
                    pvi[fm][fn] = __builtin_amdgcn_mfma_f32_16x16x32_bf16(pA, bI[fn], pvi[fm][fn], 0,0,0);
                }
            }
            __builtin_amdgcn_s_setprio(0);
        }
    }

    // ---- row-sum reduce (over 16 lrow lanes; g preserved) -> sinv LDS ----
    #pragma unroll
    for (int fm = 0; fm < 2; ++fm)
        #pragma unroll
        for (int rr = 0; rr < 4; ++rr) {
            float s = ssum[fm][rr];
            s += __shfl_xor(s, 1); s += __shfl_xor(s, 2);
            s += __shfl_xor(s, 4); s += __shfl_xor(s, 8);
            if (lrow == 0) sinv[srow0 + fm*16 + g*4 + rr] = 1.f / s;
        }
    __syncthreads();  // sinv ready (all 128 rows covered by the 4 waves)

    // epilogue: av = pv * inv[row], bf16 planar (B,S,E); av_i negated (conj V)
    const int b = bh >> 3, h = bh & 7;
    #pragma unroll
    for (int fm = 0; fm < 4; ++fm)
        #pragma unroll
        for (int fn = 0; fn < 2; ++fn) {
            const int c = wn*32 + fn*16 + lrow;
            #pragma unroll
            for (int rr = 0; rr < 4; ++rr) {
                const int rl = wr*64 + fm*16 + g*4 + rr;
                const float sc = sinv[rl];
                const int row = r0 + rl;
                const size_t addr = ((size_t)(b * Sn + row)) * En + h * Cn + c;
                avb[addr]       = f2bf( pvr[fm][fn][rr] * sc);
                avb[Qsz + addr] = f2bf(-pvi[fm][fn][rr] * sc);
            }
        }
}

// ---- K3: normalize attn rows: scale by 1/rowsum (recomputed from data).
//      grid (S/4, 64), 1 wave/row ----
template<int ST>
__global__ __launch_bounds__(256) void normalize_k(float* __restrict__ attn)
{
    const int bh = blockIdx.y;
    const int wid = threadIdx.x >> 6, lane = threadIdx.x & 63;
    const int row = blockIdx.x * 4 + wid;
    const size_t rbase = ((size_t)bh * Sn + row) * Sn;

    float v[16];
    float sum = 0.f;
    #pragma unroll
    for (int j = 0; j < 16; ++j) {
        v[j] = attn[(rbase + lane + 64*j) * (size_t)ST];
        sum += v[j];
    }
    #pragma unroll
    for (int m = 32; m >= 1; m >>= 1) sum += __shfl_xor(sum, m);
    const float inv = 1.f / sum;
    #pragma unroll
    for (int j = 0; j < 16; ++j) {
        const size_t idx = (rbase + lane + 64*j) * (size_t)ST;
        if (ST == 2) *(float2*)&attn[idx] = make_float2(v[j] * inv, 0.f);
        else         attn[idx] = v[j] * inv;
    }
}

// ---- K4: out = av(bf16) x wo^T + bo (MFMA). grid (M/128, F/64) ----
template<int ST>
__global__ __launch_bounds__(256) void out_proj_k(
    const unsigned short* __restrict__ avr, const unsigned short* __restrict__ avi,
    const float* __restrict__ wor, const float* __restrict__ woi,
    const float* __restrict__ bor, const float* __restrict__ boi,
    float* __restrict__ out)
{
    const int m0 = blockIdx.x * 128, n0 = blockIdx.y * 64;
    f32x4 accr[4][2], acci[4][2];
    const f32x4 z4 = {0.f, 0.f, 0.f, 0.f};
    #pragma unroll
    for (int fm = 0; fm < 4; ++fm)
        #pragma unroll
        for (int fn = 0; fn < 2; ++fn) { accr[fm][fn] = z4; acci[fm][fn] = z4; }

    cgemm_mfma_abf16<false>(avr, avi, m0, En, wor, woi, n0, En, En, accr, acci);

    const int lane = threadIdx.x & 63, wid = threadIdx.x >> 6;
    const int wr2 = wid >> 1, wn2 = wid & 1;
    #pragma unroll
    for (int fm = 0; fm < 4; ++fm)
        #pragma unroll
        for (int fn = 0; fn < 2; ++fn) {
            const int f = n0 + wn2*32 + fn*16 + (lane & 15);
            const float brv = bor[f], biv = boi[f];
            #pragma unroll
            for (int r = 0; r < 4; ++r) {
                const int m = m0 + wr2*64 + fm*16 + (lane >> 4)*4 + r;
                const size_t idx = ((size_t)m * Fn + f) * (size_t)ST;
                if (ST == 2)
                    *(float2*)&out[idx] = make_float2(accr[fm][fn][r] + brv, acci[fm][fn][r] + biv);
                else
                    out[idx] = accr[fm][fn][r] + brv;
            }
        }
}

template<int ST>
static void launch_all(const float* xr, const float* xi,
                       const float* wqr, const float* wqi, const float* bqr, const float* bqi,
                       const float* wkr, const float* wki, const float* bkr, const float* bki,
                       const float* wvr, const float* wvi, const float* bvr, const float* bvi,
                       const float* wor, const float* woi, const float* bor, const float* boi,
                       unsigned short* qkv, unsigned short* avb, float* out, hipStream_t stream)
{
    float* attn = out + OUT1 * ST;
    qkv_proj_k<<<dim3(Mn/128, En/64, 3), 256, 0, stream>>>(
        xr, xi, wqr, wqi, bqr, bqi, wkr, wki, bkr, bki, wvr, wvi, bvr, bvi, qkv);
    attn_fused_k<ST><<<dim3(Sn/128, Bn*Hn), 256, 0, stream>>>(qkv, attn, avb);
    normalize_k<ST><<<dim3(Sn/4, Bn*Hn), 256, 0, stream>>>(attn);
    out_proj_k<ST><<<dim3(Mn/128, Fn/64), 256, 0, stream>>>(
        avb, avb + Qsz, wor, woi, bor, boi, out);
}

extern "C" void kernel_launch(void* const* d_in, const int* in_sizes, int n_in,
                              void* d_out, int out_size, void* d_ws, size_t ws_size,
                              hipStream_t stream)
{
    // ---- host-side guards ----
    bool sizes_ok = (n_in == 18);
    if (sizes_ok) {
        sizes_ok = in_sizes[0] == XLIM && in_sizes[1] == XLIM;
        for (int g = 0; g < 3 && sizes_ok; ++g) {
            sizes_ok = in_sizes[2 + 4*g] == WLIM && in_sizes[3 + 4*g] == WLIM &&
                       in_sizes[4 + 4*g] == En  && in_sizes[5 + 4*g] == En;
        }
        sizes_ok = sizes_ok && in_sizes[14] == WLIM && in_sizes[15] == WLIM &&
                   in_sizes[16] == Fn && in_sizes[17] == Fn;
    }
    // ws: 8 bf16 planes of Qsz (q_r,q_i,k_r,k_i,v_r,v_i,av_r,av_i) = 64 MiB
    const size_t ws_needed = 8 * Qsz * sizeof(unsigned short);
    const bool ws_ok = (d_ws != nullptr) && (ws_size >= ws_needed);

    const long long fullF = 2LL * (long long)(OUT1 + ATT1);  // 142,606,336 floats
    const long long realF = (long long)(OUT1 + ATT1);        //  71,303,168 floats
    const int st = ((long long)out_size == fullF) ? 2
                 : ((long long)out_size == realF) ? 1 : 0;

    if (!sizes_ok || !ws_ok || st == 0) {
        float diag = !sizes_ok ? 3.0e9f
                   : !ws_ok    ? (float)(double)ws_size
                               : (float)out_size;
        diag_k<<<1, 1, 0, stream>>>((float*)d_out, diag);
        return;
    }

    const float* xr  = (const float*)d_in[0];
    const float* xi  = (const float*)d_in[1];
    const float* wqr = (const float*)d_in[2];
    const float* wqi = (const float*)d_in[3];
    const float* bqr = (const float*)d_in[4];
    const float* bqi = (const float*)d_in[5];
    const float* wkr = (const float*)d_in[6];
    const float* wki = (const float*)d_in[7];
    const float* bkr = (const float*)d_in[8];
    const float* bki = (const float*)d_in[9];
    const float* wvr = (const float*)d_in[10];
    const float* wvi = (const float*)d_in[11];
    const float* bvr = (const float*)d_in[12];
    const float* bvi = (const float*)d_in[13];
    const float* wor = (const float*)d_in[14];
    const float* woi = (const float*)d_in[15];
    const float* bor = (const float*)d_in[16];
    const float* boi = (const float*)d_in[17];

    unsigned short* qkv = (unsigned short*)d_ws;
    unsigned short* avb = qkv + 6 * Qsz;   // planes 6,7
    float* out = (float*)d_out;

    if (st == 2)
        launch_all<2>(xr, xi, wqr, wqi, bqr, bqi, wkr, wki, bkr, bki,
                      wvr, wvi, bvr, bvi, wor, woi, bor, boi, qkv, avb, out, stream);
    else
        launch_all<1>(xr, xi, wqr, wqi, bqr, bqi, wkr, wki, bkr, bki,
                      wvr, wvi, bvr, bvi, wor, woi, bor, boi, qkv, avb, out, stream);
}

// Round 17
// 316.231 us; speedup vs baseline: 1.2159x; 1.2159x over previous
//
#include <hip/hip_runtime.h>

// ComplexMultiheadAttention: B=8,S=1024,F=512,E=512,H=8,C=64
// Round 17: REVERT to verified best (r12 = round-11 source, 317 us total,
// fused 227 us). Post-r12 structural experiments all regressed:
//   r13/14 64-row+setprio: 244/324; r15 Q-regs 3-sync: 290/354;
//   r16 single-pass+normalize_k: 215+65/384.
// Lesson: this kernel sits in a narrow VGPR/LDS/occupancy pocket; work-saving
// restructures pay more in occupancy or new memory passes than they save.
// Structure: K1 qkv_proj (MFMA fp32->bf16 planes), K2 attn_fused (Pass A row
// sums of exp, no max needed since mag>=0 bounded; Pass B recompute + write
// normalized attn + PV MFMA -> av bf16 planes 6,7), K3 out_proj (bf16 A).

namespace {
constexpr int Bn = 8, Sn = 1024, Fn = 512, En = 512, Hn = 8, Cn = 64;
constexpr int Mn = Bn * Sn;                       // 8192
constexpr int Qszi = Bn * Hn * Sn * Cn;           // 4,194,304 per plane
constexpr size_t Qsz = (size_t)Qszi;
constexpr int XLIM = Bn * Sn * Fn;                // floats per x plane
constexpr int WLIM = En * Fn;                     // floats per weight plane
constexpr size_t OUT1 = (size_t)Bn * Sn * Fn;     // complex elems in out   (4,194,304)
constexpr size_t ATT1 = (size_t)Bn * Hn * Sn * Sn;// complex elems in attn (67,108,864)
constexpr float RDIV = 0.08838834764831845f;      // 1/sqrt(2*C) = 1/sqrt(128)
}

typedef __attribute__((ext_vector_type(8))) short short8v;  // 8 bf16 (4 VGPRs)
typedef __attribute__((ext_vector_type(4))) float f32x4;

__device__ __forceinline__ float bf2f(unsigned short u) {
    union { unsigned int u32; float f; } c; c.u32 = (unsigned int)u << 16; return c.f;
}
__device__ __forceinline__ unsigned short f2bf(float f) {
    union { float f; unsigned int u; } c; c.f = f;
    unsigned int r = (c.u + 0x7FFFu + ((c.u >> 16) & 1u)) >> 16;  // RNE
    return (unsigned short)r;
}
__device__ __forceinline__ unsigned int packbf(float lo, float hi) {
    return (unsigned int)f2bf(lo) | ((unsigned int)f2bf(hi) << 16);
}
__device__ __forceinline__ short8v neg8(short8v v) {
    union { short8v s; unsigned int u[4]; } c; c.s = v;
    #pragma unroll
    for (int j = 0; j < 4; ++j) c.u[j] ^= 0x80008000u;
    return c.s;
}
__device__ __forceinline__ float4 ld4(const float* p) { return *(const float4*)p; }

// ================= shared MFMA inner body (complex x complex, pad-40 tiles) ====
template<bool CONJB>
__device__ __forceinline__ void mfma_body(
    const short (*As_r)[40], const short (*As_i)[40],
    const short (*Bs_r)[40], const short (*Bs_i)[40],
    int wr, int wn, int lrow, int lk,
    f32x4 accr[4][2], f32x4 acci[4][2])
{
    short8v a_r[4], a_i[4], a_x[4];
    #pragma unroll
    for (int fm = 0; fm < 4; ++fm) {
        a_r[fm] = *(const short8v*)&As_r[wr*64 + fm*16 + lrow][lk];
        a_i[fm] = *(const short8v*)&As_i[wr*64 + fm*16 + lrow][lk];
        a_x[fm] = neg8(CONJB ? a_r[fm] : a_i[fm]);
    }
    short8v b_r[2], b_i[2];
    #pragma unroll
    for (int fn = 0; fn < 2; ++fn) {
        b_r[fn] = *(const short8v*)&Bs_r[wn*32 + fn*16 + lrow][lk];
        b_i[fn] = *(const short8v*)&Bs_i[wn*32 + fn*16 + lrow][lk];
    }
    #pragma unroll
    for (int fm = 0; fm < 4; ++fm)
        #pragma unroll
        for (int fn = 0; fn < 2; ++fn) {
            accr[fm][fn] = __builtin_amdgcn_mfma_f32_16x16x32_bf16(
                a_r[fm], b_r[fn], accr[fm][fn], 0, 0, 0);
            accr[fm][fn] = __builtin_amdgcn_mfma_f32_16x16x32_bf16(
                CONJB ? a_i[fm] : a_x[fm], b_i[fn], accr[fm][fn], 0, 0, 0);
            acci[fm][fn] = __builtin_amdgcn_mfma_f32_16x16x32_bf16(
                CONJB ? a_x[fm] : a_r[fm], b_i[fn], acci[fm][fn], 0, 0, 0);
            acci[fm][fn] = __builtin_amdgcn_mfma_f32_16x16x32_bf16(
                a_i[fm], b_r[fn], acci[fm][fn], 0, 0, 0);
        }
}

// ===== MFMA complex NT GEMM, fp32 x fp32 (convert at staging) — qkv_proj =====
template<bool CONJB>
__device__ __forceinline__ void cgemm_mfma(
    const float* __restrict__ Ar, const float* __restrict__ Ai, int arow0, int lda,
    const float* __restrict__ Br, const float* __restrict__ Bi, int brow0, int ldb,
    int K, f32x4 accr[4][2], f32x4 acci[4][2])
{
    __shared__ short As_r[128][40], As_i[128][40];
    __shared__ short Bs_r[64][40],  Bs_i[64][40];
    const int tid = threadIdx.x;
    const int sar = tid >> 1, sac = (tid & 1) * 16;
    const int sbr = tid >> 2, sbc = (tid & 3) * 8;
    const int wid = tid >> 6, lane = tid & 63;
    const int wr = wid >> 1, wn = wid & 1;
    const int lrow = lane & 15, lk = (lane >> 4) * 8;

    for (int k0 = 0; k0 < K; k0 += 32) {
        const float* pAr = Ar + (size_t)(arow0 + sar) * lda + k0 + sac;
        const float* pAi = Ai + (size_t)(arow0 + sar) * lda + k0 + sac;
        float4 va_r[4], va_i[4];
        #pragma unroll
        for (int q = 0; q < 4; ++q) { va_r[q] = ld4(pAr + 4*q); va_i[q] = ld4(pAi + 4*q); }
        const float* pBr = Br + (size_t)(brow0 + sbr) * ldb + k0 + sbc;
        const float* pBi = Bi + (size_t)(brow0 + sbr) * ldb + k0 + sbc;
        float4 vb_r[2], vb_i[2];
        #pragma unroll
        for (int q = 0; q < 2; ++q) { vb_r[q] = ld4(pBr + 4*q); vb_i[q] = ld4(pBi + 4*q); }

        __syncthreads();
        #pragma unroll
        for (int q = 0; q < 4; ++q) {
            *(uint2*)&As_r[sar][sac + 4*q] =
                make_uint2(packbf(va_r[q].x, va_r[q].y), packbf(va_r[q].z, va_r[q].w));
            *(uint2*)&As_i[sar][sac + 4*q] =
                make_uint2(packbf(va_i[q].x, va_i[q].y), packbf(va_i[q].z, va_i[q].w));
        }
        #pragma unroll
        for (int q = 0; q < 2; ++q) {
            *(uint2*)&Bs_r[sbr][sbc + 4*q] =
                make_uint2(packbf(vb_r[q].x, vb_r[q].y), packbf(vb_r[q].z, vb_r[q].w));
            *(uint2*)&Bs_i[sbr][sbc + 4*q] =
                make_uint2(packbf(vb_i[q].x, vb_i[q].y), packbf(vb_i[q].z, vb_i[q].w));
        }
        __syncthreads();
        mfma_body<CONJB>(As_r, As_i, Bs_r, Bs_i, wr, wn, lrow, lk, accr, acci);
    }
}

// ===== MFMA complex NT GEMM, A bf16 (direct) x B fp32 (convert) — out_proj =====
template<bool CONJB>
__device__ __forceinline__ void cgemm_mfma_abf16(
    const unsigned short* __restrict__ Ar, const unsigned short* __restrict__ Ai,
    int arow0, int lda,
    const float* __restrict__ Br, const float* __restrict__ Bi, int brow0, int ldb,
    int K, f32x4 accr[4][2], f32x4 acci[4][2])
{
    __shared__ short As_r[128][40], As_i[128][40];
    __shared__ short Bs_r[64][40],  Bs_i[64][40];
    const int tid = threadIdx.x;
    const int sar = tid >> 1, sac = (tid & 1) * 16;
    const int sbr = tid >> 2, sbc = (tid & 3) * 8;
    const int wid = tid >> 6, lane = tid & 63;
    const int wr = wid >> 1, wn = wid & 1;
    const int lrow = lane & 15, lk = (lane >> 4) * 8;

    for (int k0 = 0; k0 < K; k0 += 32) {
        const unsigned short* pAr = Ar + (size_t)(arow0 + sar) * lda + k0 + sac;
        const unsigned short* pAi = Ai + (size_t)(arow0 + sar) * lda + k0 + sac;
        short8v va_r0 = *(const short8v*)pAr;
        short8v va_r1 = *(const short8v*)(pAr + 8);
        short8v va_i0 = *(const short8v*)pAi;
        short8v va_i1 = *(const short8v*)(pAi + 8);
        const float* pBr = Br + (size_t)(brow0 + sbr) * ldb + k0 + sbc;
        const float* pBi = Bi + (size_t)(brow0 + sbr) * ldb + k0 + sbc;
        float4 vb_r[2], vb_i[2];
        #pragma unroll
        for (int q = 0; q < 2; ++q) { vb_r[q] = ld4(pBr + 4*q); vb_i[q] = ld4(pBi + 4*q); }

        __syncthreads();
        *(short8v*)&As_r[sar][sac]     = va_r0;
        *(short8v*)&As_r[sar][sac + 8] = va_r1;
        *(short8v*)&As_i[sar][sac]     = va_i0;
        *(short8v*)&As_i[sar][sac + 8] = va_i1;
        #pragma unroll
        for (int q = 0; q < 2; ++q) {
            *(uint2*)&Bs_r[sbr][sbc + 4*q] =
                make_uint2(packbf(vb_r[q].x, vb_r[q].y), packbf(vb_r[q].z, vb_r[q].w));
            *(uint2*)&Bs_i[sbr][sbc + 4*q] =
                make_uint2(packbf(vb_i[q].x, vb_i[q].y), packbf(vb_i[q].z, vb_i[q].w));
        }
        __syncthreads();
        mfma_body<CONJB>(As_r, As_i, Bs_r, Bs_i, wr, wn, lrow, lk, accr, acci);
    }
}

// ---- diagnostic ----
__global__ void diag_k(float* __restrict__ out, float v) { out[0] = v; }

// ---- K1: QKV projection (MFMA) -> bf16 planes. grid (M/128, E/64, 3) ----
__global__ __launch_bounds__(256) void qkv_proj_k(
    const float* __restrict__ xr, const float* __restrict__ xi,
    const float* __restrict__ wqr, const float* __restrict__ wqi,
    const float* __restrict__ bqr, const float* __restrict__ bqi,
    const float* __restrict__ wkr, const float* __restrict__ wki,
    const float* __restrict__ bkr, const float* __restrict__ bki,
    const float* __restrict__ wvr, const float* __restrict__ wvi,
    const float* __restrict__ bvr, const float* __restrict__ bvi,
    unsigned short* __restrict__ ws)
{
    const int which = blockIdx.z;
    const float* wr_ = which == 0 ? wqr : which == 1 ? wkr : wvr;
    const float* wi_ = which == 0 ? wqi : which == 1 ? wki : wvi;
    const float* br_ = which == 0 ? bqr : which == 1 ? bkr : bvr;
    const float* bi_ = which == 0 ? bqi : which == 1 ? bki : bvi;
    unsigned short* outr = ws + (size_t)which * 2 * Qsz;
    unsigned short* outi = outr + Qsz;

    const int m0 = blockIdx.x * 128, n0 = blockIdx.y * 64;
    f32x4 accr[4][2], acci[4][2];
    const f32x4 z4 = {0.f, 0.f, 0.f, 0.f};
    #pragma unroll
    for (int fm = 0; fm < 4; ++fm)
        #pragma unroll
        for (int fn = 0; fn < 2; ++fn) { accr[fm][fn] = z4; acci[fm][fn] = z4; }

    cgemm_mfma<false>(xr, xi, m0, Fn, wr_, wi_, n0, Fn, Fn, accr, acci);

    const int lane = threadIdx.x & 63, wid = threadIdx.x >> 6;
    const int wr2 = wid >> 1, wn2 = wid & 1;
    #pragma unroll
    for (int fm = 0; fm < 4; ++fm)
        #pragma unroll
        for (int fn = 0; fn < 2; ++fn) {
            const int e = n0 + wn2*32 + fn*16 + (lane & 15);
            const int h = e >> 6, c = e & (Cn - 1);
            const float brv = br_[e], biv = bi_[e];
            #pragma unroll
            for (int r = 0; r < 4; ++r) {
                const int m = m0 + wr2*64 + fm*16 + (lane >> 4)*4 + r;
                const int b = m >> 10, s = m & (Sn - 1);
                const size_t idx = (((size_t)(b * Hn + h)) * Sn + s) * Cn + c;
                outr[idx] = f2bf(accr[fm][fn][r] + brv);
                outi[idx] = f2bf(acci[fm][fn][r] + biv);
            }
        }
}

// ---- K2: fused score+softmax+PV. grid (S/128, 64), 256 thr (4 waves) ----
// Pass A: sum_t exp(|sim|/sqrt(2C)) per row (score recomputable, no max needed:
// mag >= 0 and bounded ~22 -> exp safe in fp32; softmax shift-invariant).
// Pass B: recompute scores, P = exp*inv, write normalized attn (mandatory),
// stage P bf16 -> LDS (overlaying K after barrier), PV MFMA -> av bf16.
template<int ST>
__global__ __launch_bounds__(256) void attn_fused_k(
    const unsigned short* __restrict__ qkv, float* __restrict__ attn,
    unsigned short* __restrict__ avb)
{
    const int bh = blockIdx.y;
    const int r0 = blockIdx.x * 128;
    const size_t poff = (size_t)bh * Sn * Cn;
    const unsigned short* qr = qkv + poff;
    const unsigned short* qi = qkv + Qsz + poff;
    const unsigned short* kr = qkv + 2 * Qsz + poff;
    const unsigned short* ki = qkv + 3 * Qsz + poff;
    const unsigned short* vr = qkv + 4 * Qsz + poff;
    const unsigned short* vi = qkv + 5 * Qsz + poff;

    __shared__ short Qr[128][68], Qi[128][68];   // 34 KB, resident
    __shared__ short KP[2][64][68];              // 17 KB: K tile, then P overlays
    __shared__ short Vtr[64][68], Vti[64][68];   // 17 KB: V^T [c][t]
    short (*Ps)[68] = (short(*)[68])KP;          // P [128][68] == KP memory

    const int tid = threadIdx.x;
    const int lane = tid & 63, wid = tid >> 6;
    const int lrow = lane & 15, g = lane >> 4, lk = g * 8;
    const int srow0 = 32 * wid;                  // score-phase: wave owns 32 rows
    const int wr = wid >> 1, wn = wid & 1;       // PV-phase 2x2

    // stage Q once: 128 rows x 64, 2 thr/row
    {
        const int row = tid >> 1, seg = (tid & 1) * 32;
        const unsigned short* pr = qr + (size_t)(r0 + row) * Cn + seg;
        const unsigned short* pi = qi + (size_t)(r0 + row) * Cn + seg;
        #pragma unroll
        for (int q = 0; q < 4; ++q) {
            *(short8v*)&Qr[row][seg + 8*q] = *(const short8v*)(pr + 8*q);
            *(short8v*)&Qi[row][seg + 8*q] = *(const short8v*)(pi + 8*q);
        }
    }
    const int kst_row = tid >> 2, kst_seg = (tid & 3) * 16;  // K stage: 4 thr/row
    const int vst_t = tid & 63, vst_c = (tid >> 6) * 16;     // V stage: 1 thr/t-row

    float ssum[2][4] = {};
    __syncthreads();  // Q ready

    // ---------- PASS A ----------
    for (int t0 = 0; t0 < Sn; t0 += 64) {
        short8v k_r0 = *(const short8v*)(kr + (size_t)(t0 + kst_row) * Cn + kst_seg);
        short8v k_r1 = *(const short8v*)(kr + (size_t)(t0 + kst_row) * Cn + kst_seg + 8);
        short8v k_i0 = *(const short8v*)(ki + (size_t)(t0 + kst_row) * Cn + kst_seg);
        short8v k_i1 = *(const short8v*)(ki + (size_t)(t0 + kst_row) * Cn + kst_seg + 8);
        __syncthreads();
        *(short8v*)&KP[0][kst_row][kst_seg]     = k_r0;
        *(short8v*)&KP[0][kst_row][kst_seg + 8] = k_r1;
        *(short8v*)&KP[1][kst_row][kst_seg]     = k_i0;
        *(short8v*)&KP[1][kst_row][kst_seg + 8] = k_i1;
        __syncthreads();

        f32x4 cr[2][4], ci[2][4];
        const f32x4 z4 = {0.f, 0.f, 0.f, 0.f};
        #pragma unroll
        for (int fm = 0; fm < 2; ++fm)
            #pragma unroll
            for (int fn = 0; fn < 4; ++fn) { cr[fm][fn] = z4; ci[fm][fn] = z4; }
        #pragma unroll
        for (int kh = 0; kh < 2; ++kh) {
            const int kof = kh*32 + lk;
            short8v br_[4], bi_[4];
            #pragma unroll
            for (int fn = 0; fn < 4; ++fn) {
                br_[fn] = *(const short8v*)&KP[0][fn*16 + lrow][kof];
                bi_[fn] = *(const short8v*)&KP[1][fn*16 + lrow][kof];
            }
            #pragma unroll
            for (int fm = 0; fm < 2; ++fm) {
                short8v ar = *(const short8v*)&Qr[srow0 + fm*16 + lrow][kof];
                short8v ai = *(const short8v*)&Qi[srow0 + fm*16 + lrow][kof];
                short8v ax = neg8(ar);
                #pragma unroll
                for (int fn = 0; fn < 4; ++fn) {
                    cr[fm][fn] = __builtin_amdgcn_mfma_f32_16x16x32_bf16(ar, br_[fn], cr[fm][fn], 0,0,0);
                    cr[fm][fn] = __builtin_amdgcn_mfma_f32_16x16x32_bf16(ai, bi_[fn], cr[fm][fn], 0,0,0);
                    ci[fm][fn] = __builtin_amdgcn_mfma_f32_16x16x32_bf16(ai, br_[fn], ci[fm][fn], 0,0,0);
                    ci[fm][fn] = __builtin_amdgcn_mfma_f32_16x16x32_bf16(ax, bi_[fn], ci[fm][fn], 0,0,0);
                }
            }
        }
        #pragma unroll
        for (int fm = 0; fm < 2; ++fm)
            #pragma unroll
            for (int rr = 0; rr < 4; ++rr) {
                float acc = 0.f;
                #pragma unroll
                for (int fn = 0; fn < 4; ++fn) {
                    const float re = cr[fm][fn][rr], im = ci[fm][fn][rr];
                    acc += __expf(sqrtf(fmaf(re, re, im*im)) * RDIV);
                }
                ssum[fm][rr] += acc;
            }
    }
    // row-sum reduce over the 16 lanes of each row group (g preserved)
    float inv[2][4];
    #pragma unroll
    for (int fm = 0; fm < 2; ++fm)
        #pragma unroll
        for (int rr = 0; rr < 4; ++rr) {
            float s = ssum[fm][rr];
            s += __shfl_xor(s, 1); s += __shfl_xor(s, 2);
            s += __shfl_xor(s, 4); s += __shfl_xor(s, 8);
            inv[fm][rr] = 1.f / s;
        }

    f32x4 pvr[4][2], pvi[4][2];
    const f32x4 z4 = {0.f, 0.f, 0.f, 0.f};
    #pragma unroll
    for (int fm = 0; fm < 4; ++fm)
        #pragma unroll
        for (int fn = 0; fn < 2; ++fn) { pvr[fm][fn] = z4; pvi[fm][fn] = z4; }

    // ---------- PASS B ----------
    for (int t0 = 0; t0 < Sn; t0 += 64) {
        short8v k_r0 = *(const short8v*)(kr + (size_t)(t0 + kst_row) * Cn + kst_seg);
        short8v k_r1 = *(const short8v*)(kr + (size_t)(t0 + kst_row) * Cn + kst_seg + 8);
        short8v k_i0 = *(const short8v*)(ki + (size_t)(t0 + kst_row) * Cn + kst_seg);
        short8v k_i1 = *(const short8v*)(ki + (size_t)(t0 + kst_row) * Cn + kst_seg + 8);
        short8v v_r0 = *(const short8v*)(vr + (size_t)(t0 + vst_t) * Cn + vst_c);
        short8v v_r1 = *(const short8v*)(vr + (size_t)(t0 + vst_t) * Cn + vst_c + 8);
        short8v v_i0 = *(const short8v*)(vi + (size_t)(t0 + vst_t) * Cn + vst_c);
        short8v v_i1 = *(const short8v*)(vi + (size_t)(t0 + vst_t) * Cn + vst_c + 8);
        __syncthreads();  // prev PV reads done
        *(short8v*)&KP[0][kst_row][kst_seg]     = k_r0;
        *(short8v*)&KP[0][kst_row][kst_seg + 8] = k_r1;
        *(short8v*)&KP[1][kst_row][kst_seg]     = k_i0;
        *(short8v*)&KP[1][kst_row][kst_seg + 8] = k_i1;
        #pragma unroll
        for (int j = 0; j < 8; ++j) {
            Vtr[vst_c + j][vst_t] = v_r0[j];
            Vtr[vst_c + 8 + j][vst_t] = v_r1[j];
            Vti[vst_c + j][vst_t] = v_i0[j];
            Vti[vst_c + 8 + j][vst_t] = v_i1[j];
        }
        __syncthreads();

        f32x4 cr[2][4], ci[2][4];
        #pragma unroll
        for (int fm = 0; fm < 2; ++fm)
            #pragma unroll
            for (int fn = 0; fn < 4; ++fn) { cr[fm][fn] = z4; ci[fm][fn] = z4; }
        #pragma unroll
        for (int kh = 0; kh < 2; ++kh) {
            const int kof = kh*32 + lk;
            short8v br_[4], bi_[4];
            #pragma unroll
            for (int fn = 0; fn < 4; ++fn) {
                br_[fn] = *(const short8v*)&KP[0][fn*16 + lrow][kof];
                bi_[fn] = *(const short8v*)&KP[1][fn*16 + lrow][kof];
            }
            #pragma unroll
            for (int fm = 0; fm < 2; ++fm) {
                short8v ar = *(const short8v*)&Qr[srow0 + fm*16 + lrow][kof];
                short8v ai = *(const short8v*)&Qi[srow0 + fm*16 + lrow][kof];
                short8v ax = neg8(ar);
                #pragma unroll
                for (int fn = 0; fn < 4; ++fn) {
                    cr[fm][fn] = __builtin_amdgcn_mfma_f32_16x16x32_bf16(ar, br_[fn], cr[fm][fn], 0,0,0);
                    cr[fm][fn] = __builtin_amdgcn_mfma_f32_16x16x32_bf16(ai, bi_[fn], cr[fm][fn], 0,0,0);
                    ci[fm][fn] = __builtin_amdgcn_mfma_f32_16x16x32_bf16(ai, br_[fn], ci[fm][fn], 0,0,0);
                    ci[fm][fn] = __builtin_amdgcn_mfma_f32_16x16x32_bf16(ax, bi_[fn], ci[fm][fn], 0,0,0);
                }
            }
        }
        // normalized P: write attn + stash values (K still being read by others)
        float pval[2][4][4];
        #pragma unroll
        for (int fm = 0; fm < 2; ++fm)
            #pragma unroll
            for (int fn = 0; fn < 4; ++fn) {
                const int t = t0 + fn*16 + lrow;
                #pragma unroll
                for (int rr = 0; rr < 4; ++rr) {
                    const float re = cr[fm][fn][rr], im = ci[fm][fn][rr];
                    const float p = __expf(sqrtf(fmaf(re, re, im*im)) * RDIV) * inv[fm][rr];
                    pval[fm][fn][rr] = p;
                    const size_t row = (size_t)bh * Sn + r0 + srow0 + fm*16 + g*4 + rr;
                    const size_t idx = (row * Sn + t) * (size_t)ST;
                    if (ST == 2) *(float2*)&attn[idx] = make_float2(p, 0.f);
                    else         attn[idx] = p;
                }
            }
        __syncthreads();  // all waves done reading K -> safe to overlay with P
        #pragma unroll
        for (int fm = 0; fm < 2; ++fm)
            #pragma unroll
            for (int fn = 0; fn < 4; ++fn)
                #pragma unroll
                for (int rr = 0; rr < 4; ++rr)
                    Ps[srow0 + fm*16 + g*4 + rr][fn*16 + lrow] = f2bf(pval[fm][fn][rr]);
        __syncthreads();  // P + V ready

        #pragma unroll
        for (int kh = 0; kh < 2; ++kh) {
            const int kof = kh*32 + lk;
            short8v bR[2], bI[2];
            #pragma unroll
            for (int fn = 0; fn < 2; ++fn) {
                bR[fn] = *(const short8v*)&Vtr[wn*32 + fn*16 + lrow][kof];
                bI[fn] = *(const short8v*)&Vti[wn*32 + fn*16 + lrow][kof];
            }
            #pragma unroll
            for (int fm = 0; fm < 4; ++fm) {
                short8v pA = *(const short8v*)&Ps[wr*64 + fm*16 + lrow][kof];
                #pragma unroll
                for (int fn = 0; fn < 2; ++fn) {
                    pvr[fm][fn] = __builtin_amdgcn_mfma_f32_16x16x32_bf16(pA, bR[fn], pvr[fm][fn], 0,0,0);
                    pvi[fm][fn] = __builtin_amdgcn_mfma_f32_16x16x32_bf16(pA, bI[fn], pvi[fm][fn], 0,0,0);
                }
            }
        }
    }

    // epilogue: av bf16 planar (B,S,E); av_i = -acc_i (conj V)
    const int b = bh >> 3, h = bh & 7;
    #pragma unroll
    for (int fm = 0; fm < 4; ++fm)
        #pragma unroll
        for (int fn = 0; fn < 2; ++fn) {
            const int c = wn*32 + fn*16 + lrow;
            #pragma unroll
            for (int rr = 0; rr < 4; ++rr) {
                const int row = r0 + wr*64 + fm*16 + g*4 + rr;
                const size_t addr = ((size_t)(b * Sn + row)) * En + h * Cn + c;
                avb[addr]       = f2bf( pvr[fm][fn][rr]);
                avb[Qsz + addr] = f2bf(-pvi[fm][fn][rr]);
            }
        }
}

// ---- K3: out = av(bf16) x wo^T + bo (MFMA). grid (M/128, F/64) ----
template<int ST>
__global__ __launch_bounds__(256) void out_proj_k(
    const unsigned short* __restrict__ avr, const unsigned short* __restrict__ avi,
    const float* __restrict__ wor, const float* __restrict__ woi,
    const float* __restrict__ bor, const float* __restrict__ boi,
    float* __restrict__ out)
{
    const int m0 = blockIdx.x * 128, n0 = blockIdx.y * 64;
    f32x4 accr[4][2], acci[4][2];
    const f32x4 z4 = {0.f, 0.f, 0.f, 0.f};
    #pragma unroll
    for (int fm = 0; fm < 4; ++fm)
        #pragma unroll
        for (int fn = 0; fn < 2; ++fn) { accr[fm][fn] = z4; acci[fm][fn] = z4; }

    cgemm_mfma_abf16<false>(avr, avi, m0, En, wor, woi, n0, En, En, accr, acci);

    const int lane = threadIdx.x & 63, wid = threadIdx.x >> 6;
    const int wr2 = wid >> 1, wn2 = wid & 1;
    #pragma unroll
    for (int fm = 0; fm < 4; ++fm)
        #pragma unroll
        for (int fn = 0; fn < 2; ++fn) {
            const int f = n0 + wn2*32 + fn*16 + (lane & 15);
            const float brv = bor[f], biv = boi[f];
            #pragma unroll
            for (int r = 0; r < 4; ++r) {
                const int m = m0 + wr2*64 + fm*16 + (lane >> 4)*4 + r;
                const size_t idx = ((size_t)m * Fn + f) * (size_t)ST;
                if (ST == 2)
                    *(float2*)&out[idx] = make_float2(accr[fm][fn][r] + brv, acci[fm][fn][r] + biv);
                else
                    out[idx] = accr[fm][fn][r] + brv;
            }
        }
}

template<int ST>
static void launch_all(const float* xr, const float* xi,
                       const float* wqr, const float* wqi, const float* bqr, const float* bqi,
                       const float* wkr, const float* wki, const float* bkr, const float* bki,
                       const float* wvr, const float* wvi, const float* bvr, const float* bvi,
                       const float* wor, const float* woi, const float* bor, const float* boi,
                       unsigned short* qkv, unsigned short* avb, float* out, hipStream_t stream)
{
    float* attn = out + OUT1 * ST;
    qkv_proj_k<<<dim3(Mn/128, En/64, 3), 256, 0, stream>>>(
        xr, xi, wqr, wqi, bqr, bqi, wkr, wki, bkr, bki, wvr, wvi, bvr, bvi, qkv);
    attn_fused_k<ST><<<dim3(Sn/128, Bn*Hn), 256, 0, stream>>>(qkv, attn, avb);
    out_proj_k<ST><<<dim3(Mn/128, Fn/64), 256, 0, stream>>>(
        avb, avb + Qsz, wor, woi, bor, boi, out);
}

extern "C" void kernel_launch(void* const* d_in, const int* in_sizes, int n_in,
                              void* d_out, int out_size, void* d_ws, size_t ws_size,
                              hipStream_t stream)
{
    // ---- host-side guards ----
    bool sizes_ok = (n_in == 18);
    if (sizes_ok) {
        sizes_ok = in_sizes[0] == XLIM && in_sizes[1] == XLIM;
        for (int g = 0; g < 3 && sizes_ok; ++g) {
            sizes_ok = in_sizes[2 + 4*g] == WLIM && in_sizes[3 + 4*g] == WLIM &&
                       in_sizes[4 + 4*g] == En  && in_sizes[5 + 4*g] == En;
        }
        sizes_ok = sizes_ok && in_sizes[14] == WLIM && in_sizes[15] == WLIM &&
                   in_sizes[16] == Fn && in_sizes[17] == Fn;
    }
    // ws: 8 bf16 planes of Qsz (q_r,q_i,k_r,k_i,v_r,v_i,av_r,av_i) = 64 MiB
    const size_t ws_needed = 8 * Qsz * sizeof(unsigned short);
    const bool ws_ok = (d_ws != nullptr) && (ws_size >= ws_needed);

    const long long fullF = 2LL * (long long)(OUT1 + ATT1);  // 142,606,336 floats
    const long long realF = (long long)(OUT1 + ATT1);        //  71,303,168 floats
    const int st = ((long long)out_size == fullF) ? 2
                 : ((long long)out_size == realF) ? 1 : 0;

    if (!sizes_ok || !ws_ok || st == 0) {
        float diag = !sizes_ok ? 3.0e9f
                   : !ws_ok    ? (float)(double)ws_size
                               : (float)out_size;
        diag_k<<<1, 1, 0, stream>>>((float*)d_out, diag);
        return;
    }

    const float* xr  = (const float*)d_in[0];
    const float* xi  = (const float*)d_in[1];
    const float* wqr = (const float*)d_in[2];
    const float* wqi = (const float*)d_in[3];
    const float* bqr = (const float*)d_in[4];
    const float* bqi = (const float*)d_in[5];
    const float* wkr = (const float*)d_in[6];
    const float* wki = (const float*)d_in[7];
    const float* bkr = (const float*)d_in[8];
    const float* bki = (const float*)d_in[9];
    const float* wvr = (const float*)d_in[10];
    const float* wvi = (const float*)d_in[11];
    const float* bvr = (const float*)d_in[12];
    const float* bvi = (const float*)d_in[13];
    const float* wor = (const float*)d_in[14];
    const float* woi = (const float*)d_in[15];
    const float* bor = (const float*)d_in[16];
    const float* boi = (const float*)d_in[17];

    unsigned short* qkv = (unsigned short*)d_ws;
    unsigned short* avb = qkv + 6 * Qsz;   // planes 6,7
    float* out = (float*)d_out;

    if (st == 2)
        launch_all<2>(xr, xi, wqr, wqi, bqr, bqi, wkr, wki, bkr, bki,
                      wvr, wvi, bvr, bvi, wor, woi, bor, boi, qkv, avb, out, stream);
    else
        launch_all<1>(xr, xi, wqr, wqi, bqr, bqi, wkr, wki, bkr, bki,
                      wvr, wvi, bvr, bvi, wor, woi, bor, boi, qkv, avb, out, stream);
}